// Round 4
// baseline (687.798 us; speedup 1.0000x reference)
//
#include <hip/hip_runtime.h>
#include <stdint.h>

#define BB 16384
#define II 512
#define HH 1024
#define OO 512

typedef short s16x8 __attribute__((ext_vector_type(8)));
typedef float f32x4 __attribute__((ext_vector_type(4)));

__device__ __forceinline__ unsigned short f2bf(float x) {
  union { float f; unsigned u; } v; v.f = x;
  return (unsigned short)((v.u + 0x7fffu + ((v.u >> 16) & 1u)) >> 16);  // RNE
}
__device__ __forceinline__ float bf2f(unsigned short b) {
  union { unsigned u; float f; } v; v.u = ((unsigned)b) << 16;
  return v.f;
}
__device__ __forceinline__ float sigmoid_f(float x) {
  return 1.0f / (1.0f + __expf(-x));
}
__device__ __forceinline__ float tanh_f(float x) {
  float ax = fabsf(x);
  float e = __expf(-2.0f * ax);
  float t = (1.0f - e) / (1.0f + e);
  return x >= 0.0f ? t : -t;
}

__device__ __forceinline__ void stage16(const void* g, void* l) {
  __builtin_amdgcn_global_load_lds((const __attribute__((address_space(1))) void*)g,
                                   (__attribute__((address_space(3))) void*)l,
                                   16, 0, 0);
}

// ---------------- fused prep kernel ----------------
__global__ __launch_bounds__(256) void prep_all(const float* __restrict__ inp,
                                                const float* __restrict__ h,
                                                const float* __restrict__ Wx,
                                                const float* __restrict__ Wh,
                                                const float* __restrict__ Wout,
                                                unsigned short* __restrict__ Xb,
                                                unsigned short* __restrict__ Hlo,
                                                unsigned short* __restrict__ Wg,
                                                unsigned short* __restrict__ Wz2,
                                                unsigned short* __restrict__ Wo) {
  const int bid = blockIdx.x;
  if (bid < 12288) {
    int t = bid * 256 + threadIdx.x;
    int base = t * 8;
    int b = base / 1536;
    int k = base - b * 1536;
    const float* src = (k < 512) ? (inp + b * 512 + k) : (h + b * 1024 + (k - 512));
    float4 v0 = *(const float4*)src;
    float4 v1 = *(const float4*)(src + 4);
    float f[8] = {v0.x, v0.y, v0.z, v0.w, v1.x, v1.y, v1.z, v1.w};
    unsigned short hi[8];
#pragma unroll
    for (int i = 0; i < 8; ++i) hi[i] = f2bf(f[i]);
    *(s16x8*)(Xb + base) = *(s16x8*)hi;
    if (k >= 512) {
      unsigned short lo[8];
#pragma unroll
      for (int i = 0; i < 8; ++i) lo[i] = f2bf(f[i] - bf2f(hi[i]));
      *(s16x8*)(Hlo + b * 1024 + (k - 512)) = *(s16x8*)lo;
    }
  } else if (bid < 15360) {
    int t = (bid - 12288) * 256 + threadIdx.x;
    int base = t * 8;
    int n = base / 1536;
    int k = base - n * 1536;
    int r = n & 127;
    int gate = (r >> 4) & 3;
    int unit = ((n >> 7) << 5) + (((r >> 6) & 1) << 4) + (r & 15);
    const float* src = (k < 512) ? (Wx + (gate * 1024 + unit) * 512 + k)
                                 : (Wh + (gate * 1024 + unit) * 1024 + (k - 512));
    float4 v0 = *(const float4*)src;
    float4 v1 = *(const float4*)(src + 4);
    float f[8] = {v0.x, v0.y, v0.z, v0.w, v1.x, v1.y, v1.z, v1.w};
    unsigned short o[8];
#pragma unroll
    for (int i = 0; i < 8; ++i) o[i] = f2bf(f[i]);
    *(s16x8*)(Wg + base) = *(s16x8*)o;
  } else if (bid < 16384) {
    int t = (bid - 15360) * 256 + threadIdx.x;
    int base = t * 8;
    int n = base >> 11;
    int k = base & 2047;
    int klo = (k < 1024) ? k : (k - 1024);
    const float* src = Wh + (size_t)3 * 1024 * 1024 + n * 1024 + klo;
    float4 v0 = *(const float4*)src;
    float4 v1 = *(const float4*)(src + 4);
    float f[8] = {v0.x, v0.y, v0.z, v0.w, v1.x, v1.y, v1.z, v1.w};
    unsigned short o[8];
    if (k < 1024) {
#pragma unroll
      for (int i = 0; i < 8; ++i) { unsigned short h_ = f2bf(f[i]); o[i] = f2bf(f[i] - bf2f(h_)); }
    } else {
#pragma unroll
      for (int i = 0; i < 8; ++i) o[i] = f2bf(f[i]);
    }
    *(s16x8*)(Wz2 + base) = *(s16x8*)o;
  } else {
    int t = (bid - 16384) * 256 + threadIdx.x;
    int base = t * 8;
    float4 v0 = *(const float4*)(Wout + base);
    float4 v1 = *(const float4*)(Wout + base + 4);
    float f[8] = {v0.x, v0.y, v0.z, v0.w, v1.x, v1.y, v1.z, v1.w};
    unsigned short o[8];
#pragma unroll
    for (int i = 0; i < 8; ++i) o[i] = f2bf(f[i]);
    *(s16x8*)(Wo + base) = *(s16x8*)o;
  }
}

// ---------------- GEMM skeleton ----------------
// BK=32, 128x128 tile, double-buffered LDS. Each buffer = 128x32 bf16 =
// 4096 shorts = 8192 B. Swizzle: logical 16B chunk j of row r at slot (j+r)&3.
// Loop: barrier; prefetch tile kk+1 -> buf[(kk+1)&1] (offset in SHORTS =
// ((kk+1)&1)*4096); compute buf[kk&1]. vmcnt(0) drain at the next barrier
// lands after a full compute phase.

#define GEMM_PROLOGUE(APTR, ALD, BPTR, BLD)                                  \
  __shared__ unsigned short As[8192];                                        \
  __shared__ unsigned short Bs[8192];                                        \
  const int tid = threadIdx.x, lane = tid & 63, wave = tid >> 6;             \
  const unsigned short *ga[2], *gb[2];                                       \
  unsigned short *laA[2], *laB[2];                                           \
  _Pragma("unroll")                                                          \
  for (int t = 0; t < 2; ++t) {                                              \
    int p = t * 256 + tid;                                                   \
    int r = p >> 2, c = p & 3, j = (c - r) & 3;                              \
    ga[t] = (APTR) + (size_t)(m0 + r) * (ALD) + j * 8;                       \
    gb[t] = (BPTR) + (size_t)(n0 + r) * (BLD) + j * 8;                       \
    laA[t] = As + (t * 256 + (tid & ~63)) * 8;                               \
    laB[t] = Bs + (t * 256 + (tid & ~63)) * 8;                               \
  }                                                                          \
  const int wm = wave & 1, wn = wave >> 1, ln = lane & 15, q = lane >> 4;    \
  int aoff[4], boff[4];                                                      \
  _Pragma("unroll")                                                          \
  for (int i = 0; i < 4; ++i) {                                              \
    int ra = wm * 64 + i * 16 + ln; aoff[i] = ra * 32 + (((q + ra) & 3) << 3); \
    int rb = wn * 64 + i * 16 + ln; boff[i] = rb * 32 + (((q + rb) & 3) << 3); \
  }                                                                          \
  f32x4 acc[4][4] = {};

#define GEMM_COMPUTE(kk)                                                     \
  {                                                                          \
    const unsigned short* A_ = As + ((kk) & 1) * 4096;                       \
    const unsigned short* B_ = Bs + ((kk) & 1) * 4096;                       \
    s16x8 af[4], bfr[4];                                                     \
    _Pragma("unroll")                                                        \
    for (int i = 0; i < 4; ++i) af[i] = *(const s16x8*)(A_ + aoff[i]);       \
    _Pragma("unroll")                                                        \
    for (int i = 0; i < 4; ++i) bfr[i] = *(const s16x8*)(B_ + boff[i]);      \
    _Pragma("unroll")                                                        \
    for (int mi = 0; mi < 4; ++mi)                                           \
      _Pragma("unroll")                                                      \
      for (int ni = 0; ni < 4; ++ni)                                         \
        acc[mi][ni] = __builtin_amdgcn_mfma_f32_16x16x32_bf16(af[mi], bfr[ni], acc[mi][ni], 0, 0, 0); \
  }

// Gate GEMM + fused LSTM epilogue. M=16384, N=4096 (permuted), K=1536.
__global__ __launch_bounds__(256) void gemm_gates(const unsigned short* __restrict__ Xb,
                                                   const unsigned short* __restrict__ Wg,
                                                   const float* __restrict__ bx,
                                                   const float* __restrict__ cold,
                                                   const unsigned short* __restrict__ Dgz,
                                                   float* __restrict__ hnew,
                                                   unsigned short* __restrict__ hnewb) {
  const int n0 = blockIdx.x * 128;
  const int m0 = blockIdx.y * 128;
  GEMM_PROLOGUE(Xb, 1536, Wg, 1536)
#pragma unroll
  for (int t = 0; t < 2; ++t) { stage16(ga[t], laA[t]); stage16(gb[t], laB[t]); }
  const int NK = 48;
  for (int kk = 0; kk < NK; ++kk) {
    __syncthreads();
    if (kk + 1 < NK) {
      const int ns = ((kk + 1) & 1) * 4096;   // buffer offset in shorts
      const int ko = (kk + 1) * 32;
#pragma unroll
      for (int t = 0; t < 2; ++t) {
        stage16(ga[t] + ko, laA[t] + ns);
        stage16(gb[t] + ko, laB[t] + ns);
      }
    }
    GEMM_COMPUTE(kk)
  }
  const int unit = (blockIdx.x << 5) + (wn << 4) + ln;
  const float bi = bx[unit];
  const float bo = bx[1024 + unit];
  const float bfg = bx[2048 + unit];
  const float bz = bx[3072 + unit];
#pragma unroll
  for (int mi = 0; mi < 4; ++mi) {
#pragma unroll
    for (int r = 0; r < 4; ++r) {
      const int b = m0 + wm * 64 + mi * 16 + q * 4 + r;
      const int idx = b * 1024 + unit;
      const float gi = acc[mi][0][r] + bi;
      const float go = acc[mi][1][r] + bo;
      const float gf = acc[mi][2][r] + bfg;
      const float gz = acc[mi][3][r] + bz + bf2f(Dgz[idx]);
      const float iv = sigmoid_f(gi);
      const float ov = sigmoid_f(go);
      const float fv = sigmoid_f(gf);
      const float zv = tanh_f(gz);
      const float cn = iv * zv + fv * cold[idx];
      const float hn = ov * tanh_f(cn);
      hnew[idx] = hn;
      hnewb[idx] = f2bf(hn);
    }
  }
}

// Dgz = h_hi x W_lo + h_lo x W_hi. M=16384, N=1024, K=2048 (two phases of 32 tiles).
__global__ __launch_bounds__(256) void gemm_zcorr(const unsigned short* __restrict__ Xb,
                                                  const unsigned short* __restrict__ Hlo,
                                                  const unsigned short* __restrict__ Wz2,
                                                  unsigned short* __restrict__ Dgz) {
  const int n0 = blockIdx.x * 128;
  const int m0 = blockIdx.y * 128;
  GEMM_PROLOGUE(Xb + 512, 1536, Wz2, 2048)   // phase-1 A = h_hi inside Xb
  const unsigned short* gaH[2];
#pragma unroll
  for (int t = 0; t < 2; ++t) {
    int p = t * 256 + tid;
    int r = p >> 2, c = p & 3, j = (c - r) & 3;
    gaH[t] = Hlo + (size_t)(m0 + r) * 1024 + j * 8;
  }
#pragma unroll
  for (int t = 0; t < 2; ++t) { stage16(ga[t], laA[t]); stage16(gb[t], laB[t]); }
  const int NK = 64;
  for (int kk = 0; kk < NK; ++kk) {
    __syncthreads();
    if (kk + 1 < NK) {
      const int nt = kk + 1;
      const int ns = (nt & 1) * 4096;         // buffer offset in shorts
#pragma unroll
      for (int t = 0; t < 2; ++t) {
        const unsigned short* srcA = (nt < 32) ? (ga[t] + nt * 32)
                                               : (gaH[t] + (nt - 32) * 32);
        stage16(srcA, laA[t] + ns);
        stage16(gb[t] + nt * 32, laB[t] + ns);
      }
    }
    GEMM_COMPUTE(kk)
  }
#pragma unroll
  for (int mi = 0; mi < 4; ++mi) {
#pragma unroll
    for (int r = 0; r < 4; ++r) {
      const int b = m0 + wm * 64 + mi * 16 + q * 4 + r;
#pragma unroll
      for (int ni = 0; ni < 4; ++ni) {
        const int n = n0 + wn * 64 + ni * 16 + ln;
        Dgz[b * 1024 + n] = f2bf(acc[mi][ni][r]);
      }
    }
  }
}

// out = h_new @ Wout^T + bout. M=16384, N=512, K=1024.
__global__ __launch_bounds__(256) void gemm_out(const unsigned short* __restrict__ Hb,
                                                const unsigned short* __restrict__ Wo,
                                                const float* __restrict__ bout,
                                                float* __restrict__ out) {
  const int n0 = blockIdx.x * 128;
  const int m0 = blockIdx.y * 128;
  GEMM_PROLOGUE(Hb, 1024, Wo, 1024)
#pragma unroll
  for (int t = 0; t < 2; ++t) { stage16(ga[t], laA[t]); stage16(gb[t], laB[t]); }
  const int NK = 32;
  for (int kk = 0; kk < NK; ++kk) {
    __syncthreads();
    if (kk + 1 < NK) {
      const int ns = ((kk + 1) & 1) * 4096;   // buffer offset in shorts
      const int ko = (kk + 1) * 32;
#pragma unroll
      for (int t = 0; t < 2; ++t) {
        stage16(ga[t] + ko, laA[t] + ns);
        stage16(gb[t] + ko, laB[t] + ns);
      }
    }
    GEMM_COMPUTE(kk)
  }
  float bo_[4];
#pragma unroll
  for (int ni = 0; ni < 4; ++ni) bo_[ni] = bout[n0 + wn * 64 + ni * 16 + ln];
#pragma unroll
  for (int mi = 0; mi < 4; ++mi) {
#pragma unroll
    for (int r = 0; r < 4; ++r) {
      const int b = m0 + wm * 64 + mi * 16 + q * 4 + r;
#pragma unroll
      for (int ni = 0; ni < 4; ++ni) {
        const int n = n0 + wn * 64 + ni * 16 + ln;
        out[b * 512 + n] = acc[mi][ni][r] + bo_[ni];
      }
    }
  }
}

extern "C" void kernel_launch(void* const* d_in, const int* in_sizes, int n_in,
                              void* d_out, int out_size, void* d_ws, size_t ws_size,
                              hipStream_t stream) {
  const float* inp  = (const float*)d_in[0];
  const float* h    = (const float*)d_in[1];
  const float* c    = (const float*)d_in[2];
  const float* Wx   = (const float*)d_in[3];
  const float* bx   = (const float*)d_in[4];
  const float* Wh   = (const float*)d_in[5];
  const float* Wout = (const float*)d_in[6];
  const float* bout = (const float*)d_in[7];

  float* out  = (float*)d_out;                       // [B, 512]
  float* hnew = out + (size_t)BB * OO;               // [B, 1024]

  char* ws = (char*)d_ws;
  unsigned short* Xb  = (unsigned short*)(ws);                  //  50,331,648 B
  unsigned short* Wg  = (unsigned short*)(ws + 50331648);       //  12,582,912 B
  unsigned short* Wo  = (unsigned short*)(ws + 62914560);       //   1,048,576 B
  unsigned short* Hb  = (unsigned short*)(ws + 63963136);       //  33,554,432 B
  unsigned short* Hlo = (unsigned short*)(ws + 97517568);       //  33,554,432 B
  unsigned short* Wz2 = (unsigned short*)(ws + 131072000);      //   4,194,304 B
  unsigned short* Dgz = (unsigned short*)(ws + 135266304);      //  33,554,432 B

  prep_all  <<<16640, 256, 0, stream>>>(inp, h, Wx, Wh, Wout, Xb, Hlo, Wg, Wz2, Wo);
  gemm_zcorr<<<dim3(8, 128),  256, 0, stream>>>(Xb, Hlo, Wz2, Dgz);
  gemm_gates<<<dim3(32, 128), 256, 0, stream>>>(Xb, Wg, bx, c, Dgz, hnew, Hb);
  gemm_out  <<<dim3(4, 128),  256, 0, stream>>>(Hb, Wo, bout, out);
}